// Round 9
// baseline (3160.533 us; speedup 1.0000x reference)
//
#include <hip/hip_runtime.h>
#include <hip/hip_bf16.h>
#include <math.h>

typedef __attribute__((ext_vector_type(8))) short bf16x8;
typedef __attribute__((ext_vector_type(4))) float f32x4;
typedef __attribute__((ext_vector_type(2))) float f32x2;

__device__ __forceinline__ float gelu_f(float x){
    float u = 0.7978845608028654f*(x + 0.044715f*x*x*x);
    float e = __expf(2.0f*u);
    float th = 1.0f - 2.0f/(e + 1.0f);
    return 0.5f*x*(1.0f + th);
}

// f32 -> bf16 bits (RNE)
__device__ __forceinline__ short f2bs(float f){
    unsigned u = __float_as_uint(f);
    u += 0x7FFF + ((u>>16)&1);
    return (short)(u>>16);
}

// ============================ Router ============================
__global__ void r_embed(const float* __restrict__ x, const float* __restrict__ ew,
                        const float* __restrict__ eb, float* __restrict__ h){
    int t = blockIdx.x*256 + threadIdx.x;           // 262144
    int d = t & 63, s = (t>>6)&127, b = t>>13;
    h[t] = x[b*16384 + s]*ew[d] + eb[d];
}

__global__ void r_qkv(const float* __restrict__ h, const float* __restrict__ w,
                      const float* __restrict__ bias, int woff, int boff,
                      float* __restrict__ qkv){
    int t = blockIdx.x*256 + threadIdx.x;           // 786432
    int j = t % 192; int sb = t/192;
    const float* hr = h + sb*64;
    float acc = bias[boff + j];
    #pragma unroll
    for(int d=0; d<64; ++d) acc += hr[d]*w[woff + d*192 + j];
    qkv[t] = acc;
}

// block = (b, hd): 128 blocks x 128 threads (one per q). K,V staged in LDS.
__global__ __launch_bounds__(128) void r_attn(const float* __restrict__ qkv,
                                              float* __restrict__ o){
    __shared__ float Ks[128][16];
    __shared__ float Vs[128][16];
    int b  = blockIdx.x >> 2;
    int hd = blockIdx.x & 3;
    int q  = threadIdx.x;                           // 0..127
    const float* base = qkv + b*128*192;
    {   // stage K/V rows for this head
        const float* kr = base + q*192 + 64  + hd*16;
        const float* vr = base + q*192 + 128 + hd*16;
        #pragma unroll
        for(int j=0;j<4;++j){
            *(float4*)&Ks[q][4*j] = *(const float4*)(kr + 4*j);
            *(float4*)&Vs[q][4*j] = *(const float4*)(vr + 4*j);
        }
    }
    float qv[16];
    {
        const float* qr = base + q*192 + hd*16;
        #pragma unroll
        for(int d=0;d<16;++d) qv[d] = qr[d];
    }
    __syncthreads();
    // pass 1: row max
    float m = -1e30f;
    #pragma unroll 4
    for(int k=0;k<128;++k){
        float acc=0.f;
        #pragma unroll
        for(int d=0;d<16;++d) acc += qv[d]*Ks[k][d];
        m = fmaxf(m, acc*0.25f);
    }
    // pass 2: exp-sum + V accumulate
    float sum=0.f; float ov[16];
    #pragma unroll
    for(int d=0;d<16;++d) ov[d]=0.f;
    #pragma unroll 2
    for(int k=0;k<128;++k){
        float acc=0.f;
        #pragma unroll
        for(int d=0;d<16;++d) acc += qv[d]*Ks[k][d];
        float p = __expf(acc*0.25f - m); sum += p;
        #pragma unroll
        for(int d=0;d<16;++d) ov[d] += p*Vs[k][d];
    }
    float inv = 1.0f/sum;
    float* orow = o + (b*128+q)*64 + hd*16;
    #pragma unroll
    for(int d=0;d<16;++d) orow[d] = ov[d]*inv;
}

__global__ void r_proj_res(const float* __restrict__ h, const float* __restrict__ o,
                           const float* __restrict__ w, const float* __restrict__ bias,
                           int woff, int boff, float* __restrict__ r){
    int t = blockIdx.x*256 + threadIdx.x;           // 262144
    int d = t & 63; int sb = t>>6;
    const float* orow = o + sb*64;
    float acc = bias[boff + d];
    #pragma unroll
    for(int e=0;e<64;++e) acc += orow[e]*w[woff + e*64 + d];
    r[t] = h[t] + acc;
}

__global__ void r_ln(const float* __restrict__ r, const float* __restrict__ s,
                     const float* __restrict__ bias, int off, float* __restrict__ h){
    int row = blockIdx.x*64 + threadIdx.x;          // 4096 rows
    const float* rr = r + row*64;
    float mu=0.f;
    #pragma unroll
    for(int d=0;d<64;++d) mu += rr[d];
    mu *= (1.0f/64.0f);
    float var=0.f;
    #pragma unroll
    for(int d=0;d<64;++d){ float df = rr[d]-mu; var += df*df; }
    var *= (1.0f/64.0f);
    float inv = rsqrtf(var + 1e-5f);
    float* hr = h + row*64;
    #pragma unroll
    for(int d=0;d<64;++d) hr[d] = (rr[d]-mu)*inv*s[off+d] + bias[off+d];
}

__global__ void r_ffn(const float* __restrict__ h, const float* __restrict__ w1,
                      const float* __restrict__ b1, const float* __restrict__ w2,
                      const float* __restrict__ b2,
                      int w1off, int b1off, int w2off, int b2off,
                      float* __restrict__ r){
    __shared__ float hrow[64];
    __shared__ float uval[256];
    int row = blockIdx.x;                           // 4096
    int tid = threadIdx.x;                          // 256
    if(tid < 64) hrow[tid] = h[row*64 + tid];
    __syncthreads();
    {
        float acc = b1[b1off + tid];
        #pragma unroll
        for(int d=0; d<64; ++d) acc += hrow[d]*w1[w1off + d*256 + tid];
        uval[tid] = fmaxf(acc, 0.0f);
    }
    __syncthreads();
    if(tid < 64){
        float acc = b2[b2off + tid];
        for(int j=0;j<256;++j) acc += uval[j]*w2[w2off + j*64 + tid];
        r[row*64 + tid] = hrow[tid] + acc;
    }
}

__global__ void r_head(const float* __restrict__ h, const float* __restrict__ fcw,
                       const float* __restrict__ fcb, int* __restrict__ idx){
    __shared__ float feats[64];
    __shared__ float lg[8];
    int b = blockIdx.x; int d = threadIdx.x;        // 64 threads
    float acc=0.f;
    for(int s2=0;s2<128;++s2) acc += h[(b*128+s2)*64 + d];
    feats[d] = acc*(1.0f/128.0f);
    __syncthreads();
    if(d<8){
        float a = fcb[d];
        for(int e=0;e<64;++e) a += feats[e]*fcw[e*8+d];
        lg[d]=a;
    }
    __syncthreads();
    if(d==0){
        int best=0; float bv=lg[0];
        for(int e=1;e<8;++e) if(lg[e]>bv){bv=lg[e];best=e;}
        idx[b]=best;
    }
}

// ============================ FNO (batch-chunked) ============================
// one-time skip-weight transpose: wt[el][o][i] = skw[el][i][o]
__global__ void f_wt(const float* __restrict__ skw, float* __restrict__ wt){
    int t = blockIdx.x*256 + threadIdx.x;           // 32768
    int el = t>>10, rem = t&1023, i = rem>>5, o = rem&31;
    wt[el*1024 + o*32 + i] = skw[el*1024 + i*32 + o];
}

__global__ void f_lift(const float* __restrict__ x, const float* __restrict__ lw,
                       const float* __restrict__ lb, const int* __restrict__ idx,
                       int b0, float* __restrict__ v){
    int t = blockIdx.x*256 + threadIdx.x;           // nb*524288
    int w = t & 127; int h2 = (t>>7)&127; int d = (t>>14)&31; int bl = t>>19;
    int b = b0 + bl;
    int e = idx[b];
    v[t] = x[b*16384 + h2*128 + w]*lw[e*32+d] + lb[e*32+d];
}

// fused forward DFT: w-DFT (radix-4 + ky recurrence) -> LDS -> h-DFT.
// ONE bi per block, 256 threads. __launch_bounds__(256,4) caps VGPR at 128
// -> 4 workgroups/CU (16 waves) to cover the twiddle-recurrence latency.
__global__ __launch_bounds__(256, 4) void f_fwd(const float* __restrict__ v,
                                                float* __restrict__ G){
    __shared__ float cT[128], sT[128];
    __shared__ float X[16*260 + 8];                 // [ky][h*2], ky-stride 260
    int tid = threadIdx.x;                          // 256
    if(tid<128){ float sv,cv; __sincosf(6.283185307179586f*tid/128.0f,&sv,&cv); cT[tid]=cv; sT[tid]=sv; }
    __syncthreads();
    int bi = blockIdx.x;
    {   // ---- phase 1: DFT along w, 8 ky modes per thread ----
        int kyg = tid>>7, h = tid&127;
        int ky0 = kyg*8;
        const float* row = v + (bi*128 + h)*128;
        float Xr[8], Xi[8];
        #pragma unroll
        for(int k=0;k<8;++k){ Xr[k]=0.f; Xi[k]=0.f; }
        #pragma unroll
        for(int j=0;j<8;++j){
            float4 a = *(const float4*)(row + 4*j);
            float4 bq= *(const float4*)(row + 4*j + 32);
            float4 c = *(const float4*)(row + 4*j + 64);
            float4 dq= *(const float4*)(row + 4*j + 96);
            #pragma unroll
            for(int r=0;r<4;++r){
                int g = 4*j + r;
                float va = (r==0)?a.x:(r==1)?a.y:(r==2)?a.z:a.w;
                float vb = (r==0)?bq.x:(r==1)?bq.y:(r==2)?bq.z:bq.w;
                float vc = (r==0)?c.x:(r==1)?c.y:(r==2)?c.z:c.w;
                float vd = (r==0)?dq.x:(r==1)?dq.y:(r==2)?dq.z:dq.w;
                float s1=va+vc, s2=vb+vd, d1=va-vc, d2=vb-vd;
                float rsum=s1+s2, rdif=s1-s2;
                float pc=cT[g], ps=-sT[g];          // p = e^{-i g θ}
                int p0 = (g*ky0)&127;               // start phase e^{-i g ky0 θ}
                float cr=cT[p0], ci=-sT[p0];
                #pragma unroll
                for(int ky=0;ky<8;++ky){            // ky0 ≡ 0 mod 4 -> same switch
                    int mm = ky&3;
                    if(mm==0){ Xr[ky]+=cr*rsum; Xi[ky]+=ci*rsum; }
                    else if(mm==1){ Xr[ky]+=cr*d1+ci*d2; Xi[ky]+=ci*d1-cr*d2; }
                    else if(mm==2){ Xr[ky]+=cr*rdif; Xi[ky]+=ci*rdif; }
                    else { Xr[ky]+=cr*d1-ci*d2; Xi[ky]+=ci*d1+cr*d2; }
                    float tt=cr*pc-ci*ps; ci=cr*ps+ci*pc; cr=tt;
                }
            }
        }
        #pragma unroll
        for(int ky=0;ky<8;++ky){
            X[(ky0+ky)*260 + h*2]   = Xr[ky];
            X[(ky0+ky)*260 + h*2+1] = Xi[ky];
        }
    }
    __syncthreads();
    {   // ---- phase 2: DFT along h at kx in {0..15,112..127}, 2 kx/thread ----
        int ky = tid&15, kg = tid>>4;               // kg 0..15
        const float* Xb = X + ky*260;
        int kxa[2] = {kg, kg+112};                  // actual kx
        float qc[2], qs[2];
        #pragma unroll
        for(int m2=0;m2<2;++m2){ qc[m2]=cT[kxa[m2]&127]; qs[m2]=-sT[kxa[m2]&127]; }
        float cr[2]={1.f,1.f}, ci[2]={0.f,0.f};
        float Gr[2]={0.f,0.f}, Gi[2]={0.f,0.f};
        for(int h=0;h<128;++h){
            float Xr=Xb[h*2], Xi2=Xb[h*2+1];
            #pragma unroll
            for(int m2=0;m2<2;++m2){
                Gr[m2] += Xr*cr[m2] - Xi2*ci[m2];
                Gi[m2] += Xr*ci[m2] + Xi2*cr[m2];
                float t=cr[m2]*qc[m2]-ci[m2]*qs[m2]; ci[m2]=cr[m2]*qs[m2]+ci[m2]*qc[m2]; cr[m2]=t;
            }
        }
        #pragma unroll
        for(int m2=0;m2<2;++m2){
            int store = kg + 16*m2;                 // compacted kxi index
            G[((bi*32+store)*16+ky)*2]   = Gr[m2];
            G[((bi*32+store)*16+ky)*2+1] = Gi[m2];
        }
    }
}

// fused spectral multiply + inverse DFT along h. Block per bo=(bl,o), 256 thr.
// __launch_bounds__(256,4): VGPR<=128 -> 4 workgroups/CU.
__global__ __launch_bounds__(256, 4) void f_spec_idft(const float* __restrict__ G,
                          const float* __restrict__ wr, const float* __restrict__ wi,
                          const int* __restrict__ idx, int l, int b0,
                          float* __restrict__ T){
    __shared__ float GoL[1024];                     // [kxi][ky] cplx
    __shared__ float cT[128], sT[128];
    int tid = threadIdx.x;                          // 256
    if(tid<128){ float sv,cv; __sincosf(6.283185307179586f*tid/128.0f,&sv,&cv); cT[tid]=cv; sT[tid]=sv; }
    int bo = blockIdx.x;                            // bl*32 + o
    int bl = bo>>5, o = bo&31;
    int e = __builtin_amdgcn_readfirstlane(idx[b0 + bl]);
    {   // ---- phase A: spectral multiply, 2 (kxi,ky) pairs per thread ----
        #pragma unroll
        for(int j=0;j<2;++j){
            int p = tid*2 + j;                      // 0..511
            int kxi = p>>4, ky = p&15;
            int side = (kxi>=16) ? 1 : 0; int xm = kxi & 15;
            int wbase = ((((e*4+l)*2+side)*32)*32 + o)*256 + xm*16 + ky;
            const float* gp = G + (bl*16384 + kxi*16 + ky)*2;   // + i*1024
            float orr=0.f, oii=0.f;
            #pragma unroll 8
            for(int i=0;i<32;++i){
                f32x2 g = *(const f32x2*)(gp + i*1024);
                float wrv = wr[wbase + i*8192];
                float wiv = wi[wbase + i*8192];
                orr += g.x*wrv - g.y*wiv;
                oii += g.x*wiv + g.y*wrv;
            }
            GoL[p*2] = orr; GoL[p*2+1] = oii;
        }
    }
    __syncthreads();
    {   // ---- phase B: inverse DFT along h, 8 ky accumulators per thread ----
        int kyg = tid>>7, h = tid&127;
        int ky0 = kyg*8;
        float Mc = cT[h], Ms = sT[h];               // e^{+i h θ}
        float Tr[8], Ti[8];
        #pragma unroll
        for(int k=0;k<8;++k){ Tr[k]=0.f; Ti[k]=0.f; }
        {   float cr=1.f, ci=0.f;
            for(int kxi=0;kxi<16;++kxi){
                #pragma unroll
                for(int ky=0;ky<8;++ky){
                    f32x2 g = *(const f32x2*)&GoL[(kxi*16+ky0+ky)*2];
                    Tr[ky] += g.x*cr - g.y*ci;
                    Ti[ky] += g.x*ci + g.y*cr;
                }
                float t=cr*Mc-ci*Ms; ci=cr*Ms+ci*Mc; cr=t;
            }
        }
        {   float cr=1.f, ci=0.f;
            for(int m=1;m<=16;++m){
                float t=cr*Mc+ci*Ms; ci=ci*Mc-cr*Ms; cr=t;   // *= conj
                int kxi = 32 - m;
                #pragma unroll
                for(int ky=0;ky<8;++ky){
                    f32x2 g = *(const f32x2*)&GoL[(kxi*16+ky0+ky)*2];
                    Tr[ky] += g.x*cr - g.y*ci;
                    Ti[ky] += g.x*ci + g.y*cr;
                }
            }
        }
        float* out = T + (bo*128 + h)*32 + ky0*2;
        #pragma unroll
        for(int k=0;k<4;++k){
            *(float4*)(out + 4*k) = make_float4(Tr[2*k], Ti[2*k], Tr[2*k+1], Ti[2*k+1]);
        }
    }
}

// C2R inverse along w (16 modes) + skip matmul + bias + gelu. IN-PLACE on v.
// T rows and transposed-W rows are BLOCK-UNIFORM -> scalar (s_load) operands.
__global__ __launch_bounds__(128) void f_inv_w_skip(const float* __restrict__ T,
                             float* __restrict__ v,
                             const float* __restrict__ wt, const float* __restrict__ skb,
                             const int* __restrict__ idx, int l, int act, int b0){
    int tid = threadIdx.x;          // 128
    int bl = blockIdx.x >> 7; int h2 = blockIdx.x & 127;
    int e = __builtin_amdgcn_readfirstlane(idx[b0 + bl]);
    int w = tid;
    const float* wte = wt + (e*4+l)*1024;           // [o][i], uniform
    const float* sbp = skb + (e*4+l)*32;
    const float* Tb  = T + (bl*32*128 + h2)*32;     // + o*4096, uniform
    // v tile column in registers as float2 pairs (static indexing only)
    f32x2 vv[16];
    #pragma unroll
    for(int i=0;i<16;++i){
        float lo = v[((bl*32+2*i  )*128+h2)*128 + w];
        float hi = v[((bl*32+2*i+1)*128+h2)*128 + w];
        vv[i].x = lo; vv[i].y = hi;
    }
    // CS[ky] = (C[ky], -S[ky]); CS[0] = (1, 0). spec = sum_ky (Tr,Ti)·CS
    f32x2 CS[16];
    {
        float bs, bc; __sincosf(6.283185307179586f*w/128.0f, &bs, &bc);
        float cr=bc, ci=bs;
        CS[0].x = 1.f; CS[0].y = 0.f;
        #pragma unroll
        for(int ky=1;ky<16;++ky){
            CS[ky].x = 2.f*cr; CS[ky].y = -2.f*ci;
            float t2=cr*bc-ci*bs; ci=cr*bs+ci*bc; cr=t2;
        }
    }
    #pragma unroll 1
    for(int o=0;o<32;o+=2){
        // ---- body o ----
        {
            const f32x2* Wp = (const f32x2*)(wte + o*32);
            const f32x2* Tp = (const f32x2*)(Tb + o*4096);
            f32x2 a  = {0.f,0.f}, a2 = {0.f,0.f};
            f32x2 s  = {0.f,0.f}, s2 = {0.f,0.f};
            #pragma unroll
            for(int k=0;k<16;k+=2){
                a  = vv[k]  *Wp[k]   + a;
                a2 = vv[k+1]*Wp[k+1] + a2;
                s  = Tp[k]  *CS[k]   + s;
                s2 = Tp[k+1]*CS[k+1] + s2;
            }
            float skip0 = sbp[o] + ((a.x+a.y)+(a2.x+a2.y));
            float spec0 = (s.x+s.y)+(s2.x+s2.y);
            float val0 = spec0*(1.0f/16384.0f) + skip0;
            if(act) val0 = gelu_f(val0);
            v[((bl*32+o)*128+h2)*128 + w] = val0;
        }
        // ---- body o+1 (independent loads, scheduler overlaps) ----
        {
            const f32x2* Wp = (const f32x2*)(wte + (o+1)*32);
            const f32x2* Tp = (const f32x2*)(Tb + (o+1)*4096);
            f32x2 a  = {0.f,0.f}, a2 = {0.f,0.f};
            f32x2 s  = {0.f,0.f}, s2 = {0.f,0.f};
            #pragma unroll
            for(int k=0;k<16;k+=2){
                a  = vv[k]  *Wp[k]   + a;
                a2 = vv[k+1]*Wp[k+1] + a2;
                s  = Tp[k]  *CS[k]   + s;
                s2 = Tp[k+1]*CS[k+1] + s2;
            }
            float skip1 = sbp[o+1] + ((a.x+a.y)+(a2.x+a2.y));
            float spec1 = (s.x+s.y)+(s2.x+s2.y);
            float val1 = spec1*(1.0f/16384.0f) + skip1;
            if(act) val1 = gelu_f(val1);
            v[((bl*32+o+1)*128+h2)*128 + w] = val1;
        }
    }
}

// final projection via MFMA bf16: per M-tile of 16 pixels,
// p1 GEMM (K=32, N=128 as 8 og tiles) -> gelu -> dot w2 -> out.
__global__ __launch_bounds__(256) void f_proj(const float* __restrict__ vin,
                       const float* __restrict__ p1w, const float* __restrict__ p1b,
                       const float* __restrict__ p2w, const float* __restrict__ p2b,
                       const int* __restrict__ idx, int b0, float* __restrict__ out){
    int tid = threadIdx.x;
    int wv  = tid>>6, lane = tid&63;
    int blk = blockIdx.x;                           // nb*32 blocks, 32 per batch
    int bl  = blk>>5; int part = blk&31;
    int b   = b0 + bl;
    int e   = __builtin_amdgcn_readfirstlane(idx[b]);
    int m   = lane&15, quad = lane>>4;
    // B-fragments (W1 tiles) + per-lane b1/w2 scalars; loaded once per wave.
    const float* w1 = p1w + e*4096;                 // [k=32][o=128]
    bf16x8 bfr[8]; float b1v[8], w2v[8];
    #pragma unroll
    for(int og=0; og<8; ++og){
        int o = og*16 + m;
        #pragma unroll
        for(int j=0;j<8;++j){
            int k = quad*8 + j;
            bfr[og][j] = f2bs(w1[k*128 + o]);
        }
        b1v[og] = p1b[e*128+o];
        w2v[og] = p2w[e*128+o];
    }
    float p2bv = p2b[e];
    const float* vbase = vin + (size_t)bl*524288;
    for(int t=0;t<8;++t){
        int tile = part*32 + wv*8 + t;              // 1024 tiles per batch
        int pix0 = tile*16;
        bf16x8 af;
        #pragma unroll
        for(int j=0;j<8;++j){
            int k = quad*8 + j;
            af[j] = f2bs(vbase[k*16384 + pix0 + m]);
        }
        float acc0=0.f, acc1=0.f, acc2=0.f, acc3=0.f;
        #pragma unroll
        for(int og=0;og<8;++og){
            f32x4 d = {0.f,0.f,0.f,0.f};
            d = __builtin_amdgcn_mfma_f32_16x16x32_bf16(af, bfr[og], d, 0,0,0);
            acc0 += w2v[og]*gelu_f(d[0]+b1v[og]);
            acc1 += w2v[og]*gelu_f(d[1]+b1v[og]);
            acc2 += w2v[og]*gelu_f(d[2]+b1v[og]);
            acc3 += w2v[og]*gelu_f(d[3]+b1v[og]);
        }
        #pragma unroll
        for(int s=1;s<16;s<<=1){
            acc0 += __shfl_xor(acc0, s, 64);
            acc1 += __shfl_xor(acc1, s, 64);
            acc2 += __shfl_xor(acc2, s, 64);
            acc3 += __shfl_xor(acc3, s, 64);
        }
        if(m==0){
            int pix = pix0 + quad*4;                // 4 consecutive pixels
            *(float4*)(out + (size_t)b*16384 + pix) =
                make_float4(acc0+p2bv, acc1+p2bv, acc2+p2bv, acc3+p2bv);
        }
    }
}

// ============================ launch ============================
extern "C" void kernel_launch(void* const* d_in, const int* in_sizes, int n_in,
                              void* d_out, int out_size, void* d_ws, size_t ws_size,
                              hipStream_t stream){
    const float* x      = (const float*)d_in[0];
    const float* enc_w  = (const float*)d_in[1];
    const float* enc_b  = (const float*)d_in[2];
    const float* qkv_w  = (const float*)d_in[3];
    const float* qkv_b  = (const float*)d_in[4];
    const float* ao_w   = (const float*)d_in[5];
    const float* ao_b   = (const float*)d_in[6];
    const float* ln1_s  = (const float*)d_in[7];
    const float* ln1_b  = (const float*)d_in[8];
    const float* ff1_w  = (const float*)d_in[9];
    const float* ff1_b  = (const float*)d_in[10];
    const float* ff2_w  = (const float*)d_in[11];
    const float* ff2_b  = (const float*)d_in[12];
    const float* ln2_s  = (const float*)d_in[13];
    const float* ln2_b  = (const float*)d_in[14];
    const float* fc_w   = (const float*)d_in[15];
    const float* fc_b   = (const float*)d_in[16];
    const float* lift_w = (const float*)d_in[17];
    const float* lift_b = (const float*)d_in[18];
    const float* spec_wr= (const float*)d_in[19];
    const float* spec_wi= (const float*)d_in[20];
    const float* skip_w = (const float*)d_in[21];
    const float* skip_b = (const float*)d_in[22];
    const float* p1_w   = (const float*)d_in[23];
    const float* p1_b   = (const float*)d_in[24];
    const float* p2_w   = (const float*)d_in[25];
    const float* p2_b   = (const float*)d_in[26];

    // workspace: header 64 fl; Wt transpose table 32768 fl; then FNO chunk of
    // nb batches = nb*851968 fl (v 524288 + spare 131072 + G 32768 + Go 32768
    // + T 131072). Router scratch (1,572,864 fl) aliases the FNO region.
    int*   idx   = (int*)d_ws + 8;
    float* wtbl  = (float*)d_ws + 64;            // 32768 floats
    float* base  = wtbl + 32768;

    size_t used_hdr = 64 + 32768;
    size_t avail_fl = (ws_size/4 > used_hdr) ? (ws_size/4 - used_hdr) : 0;
    int nb = 1;
    for(int c = 32; c >= 1; c >>= 1){
        if((size_t)c*851968 <= avail_fl){ nb = c; break; }
    }

    float* hbuf  = base;                         // 262144
    float* qkvb  = hbuf + 262144;                // 786432
    float* obuf  = qkvb + 786432;                // 262144
    float* rbuf  = obuf + 262144;                // 262144

    // ---- one-time skip-weight transpose ----
    f_wt<<<128,256,0,stream>>>(skip_w, wtbl);

    // ---- router ----
    r_embed<<<1024,256,0,stream>>>(x, enc_w, enc_b, hbuf);
    for(int l=0;l<2;++l){
        r_qkv<<<3072,256,0,stream>>>(hbuf, qkv_w, qkv_b, l*64*192, l*192, qkvb);
        r_attn<<<128,128,0,stream>>>(qkvb, obuf);
        r_proj_res<<<1024,256,0,stream>>>(hbuf, obuf, ao_w, ao_b, l*64*64, l*64, rbuf);
        r_ln<<<64,64,0,stream>>>(rbuf, ln1_s, ln1_b, l*64, hbuf);
        r_ffn<<<4096,256,0,stream>>>(hbuf, ff1_w, ff1_b, ff2_w, ff2_b,
                                     l*64*256, l*256, l*256*64, l*64, rbuf);
        r_ln<<<64,64,0,stream>>>(rbuf, ln2_s, ln2_b, l*64, hbuf);
    }
    r_head<<<32,64,0,stream>>>(hbuf, fc_w, fc_b, idx);

    // ---- FNO, batch-chunked ----
    for(int b0 = 0; b0 < 32; b0 += nb){
        float* vC = base;                        // nb*524288
        float* G  = vC + (size_t)nb*655360;      // nb*32768
        float* Go = G  + (size_t)nb*32768;       // nb*32768 (unused, layout kept)
        float* T  = Go + (size_t)nb*32768;       // nb*131072

        f_lift<<<nb*2048,256,0,stream>>>(x, lift_w, lift_b, idx, b0, vC);
        for(int l=0;l<4;++l){
            f_fwd      <<<nb*32, 256,0,stream>>>(vC, G);
            f_spec_idft<<<nb*32, 256,0,stream>>>(G, spec_wr, spec_wi, idx, l, b0, T);
            f_inv_w_skip<<<nb*128,128,0,stream>>>(T, vC, wtbl, skip_b, idx,
                                                  l, (l<3)?1:0, b0);
        }
        f_proj<<<nb*32,256,0,stream>>>(vC, p1_w, p1_b, p2_w, p2_b, idx, b0,
                                       (float*)d_out);
    }
}

// Round 10
// 973.285 us; speedup vs baseline: 3.2473x; 3.2473x over previous
//
#include <hip/hip_runtime.h>
#include <hip/hip_bf16.h>
#include <math.h>

typedef __attribute__((ext_vector_type(8))) short bf16x8;
typedef __attribute__((ext_vector_type(4))) float f32x4;
typedef __attribute__((ext_vector_type(2))) float f32x2;

__device__ __forceinline__ float gelu_f(float x){
    float u = 0.7978845608028654f*(x + 0.044715f*x*x*x);
    float e = __expf(2.0f*u);
    float th = 1.0f - 2.0f/(e + 1.0f);
    return 0.5f*x*(1.0f + th);
}

// f32 -> bf16 bits (RNE)
__device__ __forceinline__ short f2bs(float f){
    unsigned u = __float_as_uint(f);
    u += 0x7FFF + ((u>>16)&1);
    return (short)(u>>16);
}

// ============================ Router ============================
__global__ void r_embed(const float* __restrict__ x, const float* __restrict__ ew,
                        const float* __restrict__ eb, float* __restrict__ h){
    int t = blockIdx.x*256 + threadIdx.x;           // 262144
    int d = t & 63, s = (t>>6)&127, b = t>>13;
    h[t] = x[b*16384 + s]*ew[d] + eb[d];
}

__global__ void r_qkv(const float* __restrict__ h, const float* __restrict__ w,
                      const float* __restrict__ bias, int woff, int boff,
                      float* __restrict__ qkv){
    int t = blockIdx.x*256 + threadIdx.x;           // 786432
    int j = t % 192; int sb = t/192;
    const float* hr = h + sb*64;
    float acc = bias[boff + j];
    #pragma unroll
    for(int d=0; d<64; ++d) acc += hr[d]*w[woff + d*192 + j];
    qkv[t] = acc;
}

// block = (b, hd): 128 blocks x 128 threads (one per q). K,V staged in LDS.
__global__ __launch_bounds__(128) void r_attn(const float* __restrict__ qkv,
                                              float* __restrict__ o){
    __shared__ float Ks[128][16];
    __shared__ float Vs[128][16];
    int b  = blockIdx.x >> 2;
    int hd = blockIdx.x & 3;
    int q  = threadIdx.x;                           // 0..127
    const float* base = qkv + b*128*192;
    {   // stage K/V rows for this head
        const float* kr = base + q*192 + 64  + hd*16;
        const float* vr = base + q*192 + 128 + hd*16;
        #pragma unroll
        for(int j=0;j<4;++j){
            *(float4*)&Ks[q][4*j] = *(const float4*)(kr + 4*j);
            *(float4*)&Vs[q][4*j] = *(const float4*)(vr + 4*j);
        }
    }
    float qv[16];
    {
        const float* qr = base + q*192 + hd*16;
        #pragma unroll
        for(int d=0;d<16;++d) qv[d] = qr[d];
    }
    __syncthreads();
    // pass 1: row max
    float m = -1e30f;
    #pragma unroll 4
    for(int k=0;k<128;++k){
        float acc=0.f;
        #pragma unroll
        for(int d=0;d<16;++d) acc += qv[d]*Ks[k][d];
        m = fmaxf(m, acc*0.25f);
    }
    // pass 2: exp-sum + V accumulate
    float sum=0.f; float ov[16];
    #pragma unroll
    for(int d=0;d<16;++d) ov[d]=0.f;
    #pragma unroll 2
    for(int k=0;k<128;++k){
        float acc=0.f;
        #pragma unroll
        for(int d=0;d<16;++d) acc += qv[d]*Ks[k][d];
        float p = __expf(acc*0.25f - m); sum += p;
        #pragma unroll
        for(int d=0;d<16;++d) ov[d] += p*Vs[k][d];
    }
    float inv = 1.0f/sum;
    float* orow = o + (b*128+q)*64 + hd*16;
    #pragma unroll
    for(int d=0;d<16;++d) orow[d] = ov[d]*inv;
}

__global__ void r_proj_res(const float* __restrict__ h, const float* __restrict__ o,
                           const float* __restrict__ w, const float* __restrict__ bias,
                           int woff, int boff, float* __restrict__ r){
    int t = blockIdx.x*256 + threadIdx.x;           // 262144
    int d = t & 63; int sb = t>>6;
    const float* orow = o + sb*64;
    float acc = bias[boff + d];
    #pragma unroll
    for(int e=0;e<64;++e) acc += orow[e]*w[woff + e*64 + d];
    r[t] = h[t] + acc;
}

__global__ void r_ln(const float* __restrict__ r, const float* __restrict__ s,
                     const float* __restrict__ bias, int off, float* __restrict__ h){
    int row = blockIdx.x*64 + threadIdx.x;          // 4096 rows
    const float* rr = r + row*64;
    float mu=0.f;
    #pragma unroll
    for(int d=0;d<64;++d) mu += rr[d];
    mu *= (1.0f/64.0f);
    float var=0.f;
    #pragma unroll
    for(int d=0;d<64;++d){ float df = rr[d]-mu; var += df*df; }
    var *= (1.0f/64.0f);
    float inv = rsqrtf(var + 1e-5f);
    float* hr = h + row*64;
    #pragma unroll
    for(int d=0;d<64;++d) hr[d] = (rr[d]-mu)*inv*s[off+d] + bias[off+d];
}

__global__ void r_ffn(const float* __restrict__ h, const float* __restrict__ w1,
                      const float* __restrict__ b1, const float* __restrict__ w2,
                      const float* __restrict__ b2,
                      int w1off, int b1off, int w2off, int b2off,
                      float* __restrict__ r){
    __shared__ float hrow[64];
    __shared__ float uval[256];
    int row = blockIdx.x;                           // 4096
    int tid = threadIdx.x;                          // 256
    if(tid < 64) hrow[tid] = h[row*64 + tid];
    __syncthreads();
    {
        float acc = b1[b1off + tid];
        #pragma unroll
        for(int d=0; d<64; ++d) acc += hrow[d]*w1[w1off + d*256 + tid];
        uval[tid] = fmaxf(acc, 0.0f);
    }
    __syncthreads();
    if(tid < 64){
        float acc = b2[b2off + tid];
        for(int j=0;j<256;++j) acc += uval[j]*w2[w2off + j*64 + tid];
        r[row*64 + tid] = hrow[tid] + acc;
    }
}

__global__ void r_head(const float* __restrict__ h, const float* __restrict__ fcw,
                       const float* __restrict__ fcb, int* __restrict__ idx){
    __shared__ float feats[64];
    __shared__ float lg[8];
    int b = blockIdx.x; int d = threadIdx.x;        // 64 threads
    float acc=0.f;
    for(int s2=0;s2<128;++s2) acc += h[(b*128+s2)*64 + d];
    feats[d] = acc*(1.0f/128.0f);
    __syncthreads();
    if(d<8){
        float a = fcb[d];
        for(int e=0;e<64;++e) a += feats[e]*fcw[e*8+d];
        lg[d]=a;
    }
    __syncthreads();
    if(d==0){
        int best=0; float bv=lg[0];
        for(int e=1;e<8;++e) if(lg[e]>bv){bv=lg[e];best=e;}
        idx[b]=best;
    }
}

// ============================ FNO (batch-chunked) ============================
__global__ void f_lift(const float* __restrict__ x, const float* __restrict__ lw,
                       const float* __restrict__ lb, const int* __restrict__ idx,
                       int b0, float* __restrict__ v){
    int t = blockIdx.x*256 + threadIdx.x;           // nb*524288
    int w = t & 127; int h2 = (t>>7)&127; int d = (t>>14)&31; int bl = t>>19;
    int b = b0 + bl;
    int e = idx[b];
    v[t] = x[b*16384 + h2*128 + w]*lw[e*32+d] + lb[e*32+d];
}

// fused forward DFT: w-DFT (radix-4 + ky recurrence) -> LDS -> h-DFT.
// Block handles 2 bi = (bl*32+i). Output G[bi][kxi][ky] complex. (layers 1..3)
__global__ __launch_bounds__(256) void f_fwd(const float* __restrict__ v,
                                             float* __restrict__ G){
    __shared__ float cT[128], sT[128];
    __shared__ float X[2*16*260 + 8];               // [bil][ky][h*2], ky-stride 260
    int tid = threadIdx.x;                          // 256
    if(tid<128){ float sv,cv; __sincosf(6.283185307179586f*tid/128.0f,&sv,&cv); cT[tid]=cv; sT[tid]=sv; }
    __syncthreads();
    int bi0 = blockIdx.x*2;
    {   // ---- phase 1: DFT along w for 16 ky modes ----
        int bil = tid>>7, h = tid&127;
        const float* row = v + ((bi0+bil)*128 + h)*128;
        float Xr[16], Xi[16];
        #pragma unroll
        for(int k=0;k<16;++k){ Xr[k]=0.f; Xi[k]=0.f; }
        #pragma unroll
        for(int j=0;j<8;++j){
            float4 a = *(const float4*)(row + 4*j);
            float4 bq= *(const float4*)(row + 4*j + 32);
            float4 c = *(const float4*)(row + 4*j + 64);
            float4 dq= *(const float4*)(row + 4*j + 96);
            #pragma unroll
            for(int r=0;r<4;++r){
                int g = 4*j + r;
                float va = (r==0)?a.x:(r==1)?a.y:(r==2)?a.z:a.w;
                float vb = (r==0)?bq.x:(r==1)?bq.y:(r==2)?bq.z:bq.w;
                float vc = (r==0)?c.x:(r==1)?c.y:(r==2)?c.z:c.w;
                float vd = (r==0)?dq.x:(r==1)?dq.y:(r==2)?dq.z:dq.w;
                float s1=va+vc, s2=vb+vd, d1=va-vc, d2=vb-vd;
                float rsum=s1+s2, rdif=s1-s2;
                float pc=cT[g], ps=-sT[g];          // p = e^{-i g θ}
                float cr=1.f, ci=0.f;
                #pragma unroll
                for(int ky=0;ky<16;++ky){
                    int mm = ky&3;
                    if(mm==0){ Xr[ky]+=cr*rsum; Xi[ky]+=ci*rsum; }
                    else if(mm==1){ Xr[ky]+=cr*d1+ci*d2; Xi[ky]+=ci*d1-cr*d2; }
                    else if(mm==2){ Xr[ky]+=cr*rdif; Xi[ky]+=ci*rdif; }
                    else { Xr[ky]+=cr*d1-ci*d2; Xi[ky]+=ci*d1+cr*d2; }
                    float tt=cr*pc-ci*ps; ci=cr*ps+ci*pc; cr=tt;
                }
            }
        }
        float* Xb = X + bil*4160;
        #pragma unroll
        for(int ky=0;ky<16;++ky){
            Xb[ky*260 + h*2]   = Xr[ky];
            Xb[ky*260 + h*2+1] = Xi[ky];
        }
    }
    __syncthreads();
    {   // ---- phase 2: DFT along h at kx in {0..15,112..127} ----
        int ky = tid&15, kg = (tid>>4)&7, bil = tid>>7;
        int bi = bi0 + bil;
        const float* Xb = X + bil*4160 + ky*260;
        int kxs[4] = {kg, kg+8, kg+112, kg+120};
        float qc[4], qs[4];
        #pragma unroll
        for(int m2=0;m2<4;++m2){ qc[m2]=cT[kxs[m2]&127]; qs[m2]=-sT[kxs[m2]&127]; }
        float cr[4]={1.f,1.f,1.f,1.f}, ci[4]={0.f,0.f,0.f,0.f};
        float Gr[4]={0.f,0.f,0.f,0.f}, Gi[4]={0.f,0.f,0.f,0.f};
        for(int h=0;h<128;++h){
            float Xr=Xb[h*2], Xi2=Xb[h*2+1];
            #pragma unroll
            for(int m2=0;m2<4;++m2){
                Gr[m2] += Xr*cr[m2] - Xi2*ci[m2];
                Gi[m2] += Xr*ci[m2] + Xi2*cr[m2];
                float t=cr[m2]*qc[m2]-ci[m2]*qs[m2]; ci[m2]=cr[m2]*qs[m2]+ci[m2]*qc[m2]; cr[m2]=t;
            }
        }
        #pragma unroll
        for(int m2=0;m2<4;++m2){
            int kxi = kg + 8*m2;
            G[((bi*32+kxi)*16+ky)*2]   = Gr[m2];
            G[((bi*32+kxi)*16+ky)*2+1] = Gi[m2];
        }
    }
}

// DFT of the RAW INPUT image x (one image per block, 256 thr). Used for l=0:
// v(l=0)=lw*x+lb is affine in x, DFT is linear -> G_d = lw*Gx + lb*16384*dc.
__global__ __launch_bounds__(256) void f_fwd_x(const float* __restrict__ x,
                                               int b0, float* __restrict__ Gx){
    __shared__ float cT[128], sT[128];
    __shared__ float X[16*260 + 8];                 // [ky][h*2], ky-stride 260
    int tid = threadIdx.x;                          // 256
    if(tid<128){ float sv,cv; __sincosf(6.283185307179586f*tid/128.0f,&sv,&cv); cT[tid]=cv; sT[tid]=sv; }
    __syncthreads();
    int bl = blockIdx.x;
    {   // ---- phase 1: DFT along w, 8 ky modes per thread ----
        int kyg = tid>>7, h = tid&127;
        int ky0 = kyg*8;
        const float* row = x + (b0+bl)*16384 + h*128;
        float Xr[8], Xi[8];
        #pragma unroll
        for(int k=0;k<8;++k){ Xr[k]=0.f; Xi[k]=0.f; }
        #pragma unroll
        for(int j=0;j<8;++j){
            float4 a = *(const float4*)(row + 4*j);
            float4 bq= *(const float4*)(row + 4*j + 32);
            float4 c = *(const float4*)(row + 4*j + 64);
            float4 dq= *(const float4*)(row + 4*j + 96);
            #pragma unroll
            for(int r=0;r<4;++r){
                int g = 4*j + r;
                float va = (r==0)?a.x:(r==1)?a.y:(r==2)?a.z:a.w;
                float vb = (r==0)?bq.x:(r==1)?bq.y:(r==2)?bq.z:bq.w;
                float vc = (r==0)?c.x:(r==1)?c.y:(r==2)?c.z:c.w;
                float vd = (r==0)?dq.x:(r==1)?dq.y:(r==2)?dq.z:dq.w;
                float s1=va+vc, s2=vb+vd, d1=va-vc, d2=vb-vd;
                float rsum=s1+s2, rdif=s1-s2;
                float pc=cT[g], ps=-sT[g];          // p = e^{-i g θ}
                int p0 = (g*ky0)&127;               // start phase e^{-i g ky0 θ}
                float cr=cT[p0], ci=-sT[p0];
                #pragma unroll
                for(int ky=0;ky<8;++ky){            // ky0 ≡ 0 mod 4 -> same switch
                    int mm = ky&3;
                    if(mm==0){ Xr[ky]+=cr*rsum; Xi[ky]+=ci*rsum; }
                    else if(mm==1){ Xr[ky]+=cr*d1+ci*d2; Xi[ky]+=ci*d1-cr*d2; }
                    else if(mm==2){ Xr[ky]+=cr*rdif; Xi[ky]+=ci*rdif; }
                    else { Xr[ky]+=cr*d1-ci*d2; Xi[ky]+=ci*d1+cr*d2; }
                    float tt=cr*pc-ci*ps; ci=cr*ps+ci*pc; cr=tt;
                }
            }
        }
        #pragma unroll
        for(int ky=0;ky<8;++ky){
            X[(ky0+ky)*260 + h*2]   = Xr[ky];
            X[(ky0+ky)*260 + h*2+1] = Xi[ky];
        }
    }
    __syncthreads();
    {   // ---- phase 2: DFT along h at kx in {0..15,112..127}, 2 kx/thread ----
        int ky = tid&15, kg = tid>>4;               // kg 0..15
        const float* Xb = X + ky*260;
        int kxa[2] = {kg, kg+112};                  // actual kx
        float qc[2], qs[2];
        #pragma unroll
        for(int m2=0;m2<2;++m2){ qc[m2]=cT[kxa[m2]&127]; qs[m2]=-sT[kxa[m2]&127]; }
        float cr[2]={1.f,1.f}, ci[2]={0.f,0.f};
        float Gr[2]={0.f,0.f}, Gi[2]={0.f,0.f};
        for(int h=0;h<128;++h){
            float Xr=Xb[h*2], Xi2=Xb[h*2+1];
            #pragma unroll
            for(int m2=0;m2<2;++m2){
                Gr[m2] += Xr*cr[m2] - Xi2*ci[m2];
                Gi[m2] += Xr*ci[m2] + Xi2*cr[m2];
                float t=cr[m2]*qc[m2]-ci[m2]*qs[m2]; ci[m2]=cr[m2]*qs[m2]+ci[m2]*qc[m2]; cr[m2]=t;
            }
        }
        #pragma unroll
        for(int m2=0;m2<2;++m2){
            int store = kg + 16*m2;                 // compacted kxi index
            Gx[bl*1024 + (store*16+ky)*2]   = Gr[m2];
            Gx[bl*1024 + (store*16+ky)*2+1] = Gi[m2];
        }
    }
}

// layer-0 G from Gx: G[bl][d][p] = lw[e,d]*Gx[bl][p] (+ lb[e,d]*16384 at p==0)
__global__ void f_scale(const float* __restrict__ Gx, const float* __restrict__ lw,
                        const float* __restrict__ lb, const int* __restrict__ idx,
                        int b0, float* __restrict__ G){
    int t = blockIdx.x*256 + threadIdx.x;           // nb*16384 complex elems
    int p = t & 511; int d = (t>>9)&31; int bl = t>>14;
    int e = idx[b0 + bl];
    float a = lw[e*32+d];
    float gr = Gx[bl*1024 + p*2], gi = Gx[bl*1024 + p*2+1];
    float orr = a*gr, oii = a*gi;
    if(p==0) orr += lb[e*32+d]*16384.0f;
    G[t*2] = orr; G[t*2+1] = oii;
}

__global__ void f_specmul(const float* __restrict__ G, const float* __restrict__ wr,
                          const float* __restrict__ wi, const int* __restrict__ idx,
                          int l, int b0, float* __restrict__ Go){
    int t = blockIdx.x*256 + threadIdx.x;           // nb*16384
    int ky = t & 15; int kxi = (t>>4)&31; int o = (t>>9)&31; int bl = t>>14;
    int e = __builtin_amdgcn_readfirstlane(idx[b0 + bl]);
    int side = (kxi>=16) ? 1 : 0; int xm = kxi & 15;
    int wbase = ((((e*4+l)*2+side)*32)*32 + o)*256 + xm*16 + ky;
    const float* gp = G + ((bl*1024 + kxi)*16 + ky)*2;
    float orr=0.f, oii=0.f;
    #pragma unroll 8
    for(int i=0;i<32;++i){
        float gr = gp[i*1024], gi = gp[i*1024+1];
        float wrv = wr[wbase + i*8192];
        float wiv = wi[wbase + i*8192];
        orr += gr*wrv - gi*wiv;
        oii += gr*wiv + gi*wrv;
    }
    Go[t*2]=orr; Go[t*2+1]=oii;
}

// inverse DFT along h. Block per bo=(bl,o), thread=h.
__global__ __launch_bounds__(128) void f_idft_h(const float* __restrict__ Go,
                                                float* __restrict__ T){
    __shared__ float cT[128], sT[128];
    int tid = threadIdx.x;                          // 128
    { float sv,cv; __sincosf(6.283185307179586f*tid/128.0f,&sv,&cv); cT[tid]=cv; sT[tid]=sv; }
    __syncthreads();
    int bo = blockIdx.x;
    const float* g = Go + bo*1024;                  // [kxi][ky] cplx
    int h = tid;
    float Mc = cT[h], Ms = sT[h];                   // e^{+i h θ}
    float Tr[16], Ti[16];
    #pragma unroll
    for(int k=0;k<16;++k){ Tr[k]=0.f; Ti[k]=0.f; }
    {   float cr=1.f, ci=0.f;
        for(int kxi=0;kxi<16;++kxi){
            #pragma unroll
            for(int ky=0;ky<16;++ky){
                float gr=g[(kxi*16+ky)*2], gi=g[(kxi*16+ky)*2+1];
                Tr[ky] += gr*cr - gi*ci;
                Ti[ky] += gr*ci + gi*cr;
            }
            float t=cr*Mc-ci*Ms; ci=cr*Ms+ci*Mc; cr=t;
        }
    }
    {   float cr=1.f, ci=0.f;
        for(int m=1;m<=16;++m){
            float t=cr*Mc+ci*Ms; ci=ci*Mc-cr*Ms; cr=t;   // *= conj
            int kxi = 32 - m;
            #pragma unroll
            for(int ky=0;ky<16;++ky){
                float gr=g[(kxi*16+ky)*2], gi=g[(kxi*16+ky)*2+1];
                Tr[ky] += gr*cr - gi*ci;
                Ti[ky] += gr*ci + gi*cr;
            }
        }
    }
    float* out = T + (bo*128 + h)*32;
    #pragma unroll
    for(int k=0;k<8;++k){
        *(float4*)(out + 4*k) = make_float4(Tr[2*k], Ti[2*k], Tr[2*k+1], Ti[2*k+1]);
    }
}

// C2R inverse along w (16 modes) + skip matmul + bias + gelu. IN-PLACE on v.
// Packed-f32 form: all dots expressed as float2 elementwise FMA so the
// compiler emits v_pk_fma_f32. LDS-staged T/W tiles, conflict-free staging.
__global__ __launch_bounds__(128) void f_inv_w_skip(const float* __restrict__ T,
                             float* __restrict__ v,
                             const float* __restrict__ skw, const float* __restrict__ skb,
                             const int* __restrict__ idx, int l, int act, int b0){
    __shared__ float Tl[1024];      // [o][j]  32 x 32 floats (Tr,Ti interleaved)
    __shared__ float Wl[1024];      // [o][i]  transposed skip weights
    int tid = threadIdx.x;          // 128
    int bl = blockIdx.x >> 7; int h2 = blockIdx.x & 127;
    int e = __builtin_amdgcn_readfirstlane(idx[b0 + bl]);
    int w = tid;
    const float* swp = skw + (e*4+l)*1024;
    const float* sbp = skb + (e*4+l)*32;
    {   // stage T tile: flat lane-consecutive b128 writes (conflict-free)
        #pragma unroll
        for(int rep=0; rep<2; ++rep){
            int g = rep*512 + tid*4;
            int o = g>>5, j = g&31;
            *(float4*)&Tl[g] = *(const float4*)(T + ((bl*32+o)*128 + h2)*32 + j);
        }
        // stage W transposed: src flat idx g=t*8 -> i=t>>2, o0=(t&3)*8
        int gi = tid>>2, go = (tid&3)*8;
        float4 wa = *(const float4*)(swp + gi*32 + go);
        float4 wb = *(const float4*)(swp + gi*32 + go + 4);
        Wl[(go+0)*32+gi]=wa.x; Wl[(go+1)*32+gi]=wa.y;
        Wl[(go+2)*32+gi]=wa.z; Wl[(go+3)*32+gi]=wa.w;
        Wl[(go+4)*32+gi]=wb.x; Wl[(go+5)*32+gi]=wb.y;
        Wl[(go+6)*32+gi]=wb.z; Wl[(go+7)*32+gi]=wb.w;
    }
    // v tile column in registers as float2 pairs (static indexing only)
    f32x2 vv[16];
    #pragma unroll
    for(int i=0;i<16;++i){
        float lo = v[((bl*32+2*i  )*128+h2)*128 + w];
        float hi = v[((bl*32+2*i+1)*128+h2)*128 + w];
        vv[i].x = lo; vv[i].y = hi;
    }
    // CS[ky] = (C[ky], -S[ky]); CS[0] = (1, 0). spec = sum_ky (Tr,Ti)·CS
    f32x2 CS[16];
    {
        float bs, bc; __sincosf(6.283185307179586f*w/128.0f, &bs, &bc);
        float cr=bc, ci=bs;
        CS[0].x = 1.f; CS[0].y = 0.f;
        #pragma unroll
        for(int ky=1;ky<16;++ky){
            CS[ky].x = 2.f*cr; CS[ky].y = -2.f*ci;
            float t2=cr*bc-ci*bs; ci=cr*bs+ci*bc; cr=t2;
        }
    }
    __syncthreads();
    #pragma unroll 1
    for(int o=0;o<32;o+=2){
        const f32x2* W0 = (const f32x2*)&Wl[o*32];
        const f32x2* W1 = (const f32x2*)&Wl[o*32+32];
        const f32x2* T0 = (const f32x2*)&Tl[o*32];
        const f32x2* T1 = (const f32x2*)&Tl[o*32+32];
        f32x2 a  = {0.f,0.f}, a2 = {0.f,0.f};   // skip acc, output o
        f32x2 b  = {0.f,0.f}, b2 = {0.f,0.f};   // skip acc, output o+1
        f32x2 s  = {0.f,0.f}, s2 = {0.f,0.f};   // spec acc, output o
        f32x2 t  = {0.f,0.f}, t2 = {0.f,0.f};   // spec acc, output o+1
        #pragma unroll
        for(int k=0;k<16;k+=2){
            a  = vv[k]  *W0[k]   + a;
            a2 = vv[k+1]*W0[k+1] + a2;
            b  = vv[k]  *W1[k]   + b;
            b2 = vv[k+1]*W1[k+1] + b2;
            s  = T0[k]  *CS[k]   + s;
            s2 = T0[k+1]*CS[k+1] + s2;
            t  = T1[k]  *CS[k]   + t;
            t2 = T1[k+1]*CS[k+1] + t2;
        }
        float skip0 = sbp[o]   + ((a.x+a.y)+(a2.x+a2.y));
        float skip1 = sbp[o+1] + ((b.x+b.y)+(b2.x+b2.y));
        float spec0 = (s.x+s.y)+(s2.x+s2.y);
        float spec1 = (t.x+t.y)+(t2.x+t2.y);
        float val0 = spec0*(1.0f/16384.0f) + skip0;
        float val1 = spec1*(1.0f/16384.0f) + skip1;
        if(act){ val0 = gelu_f(val0); val1 = gelu_f(val1); }
        v[((bl*32+o  )*128+h2)*128 + w] = val0;
        v[((bl*32+o+1)*128+h2)*128 + w] = val1;
    }
}

// final projection via MFMA bf16: per M-tile of 16 pixels,
// p1 GEMM (K=32, N=128 as 8 og tiles) -> gelu -> dot w2 -> out.
__global__ __launch_bounds__(256) void f_proj(const float* __restrict__ vin,
                       const float* __restrict__ p1w, const float* __restrict__ p1b,
                       const float* __restrict__ p2w, const float* __restrict__ p2b,
                       const int* __restrict__ idx, int b0, float* __restrict__ out){
    int tid = threadIdx.x;
    int wv  = tid>>6, lane = tid&63;
    int blk = blockIdx.x;                           // nb*32 blocks, 32 per batch
    int bl  = blk>>5; int part = blk&31;
    int b   = b0 + bl;
    int e   = __builtin_amdgcn_readfirstlane(idx[b]);
    int m   = lane&15, quad = lane>>4;
    // B-fragments (W1 tiles) + per-lane b1/w2 scalars; loaded once per wave.
    const float* w1 = p1w + e*4096;                 // [k=32][o=128]
    bf16x8 bfr[8]; float b1v[8], w2v[8];
    #pragma unroll
    for(int og=0; og<8; ++og){
        int o = og*16 + m;
        #pragma unroll
        for(int j=0;j<8;++j){
            int k = quad*8 + j;
            bfr[og][j] = f2bs(w1[k*128 + o]);
        }
        b1v[og] = p1b[e*128+o];
        w2v[og] = p2w[e*128+o];
    }
    float p2bv = p2b[e];
    const float* vbase = vin + (size_t)bl*524288;
    for(int t=0;t<8;++t){
        int tile = part*32 + wv*8 + t;              // 1024 tiles per batch
        int pix0 = tile*16;
        bf16x8 af;
        #pragma unroll
        for(int j=0;j<8;++j){
            int k = quad*8 + j;
            af[j] = f2bs(vbase[k*16384 + pix0 + m]);
        }
        float acc0=0.f, acc1=0.f, acc2=0.f, acc3=0.f;
        #pragma unroll
        for(int og=0;og<8;++og){
            f32x4 d = {0.f,0.f,0.f,0.f};
            d = __builtin_amdgcn_mfma_f32_16x16x32_bf16(af, bfr[og], d, 0,0,0);
            acc0 += w2v[og]*gelu_f(d[0]+b1v[og]);
            acc1 += w2v[og]*gelu_f(d[1]+b1v[og]);
            acc2 += w2v[og]*gelu_f(d[2]+b1v[og]);
            acc3 += w2v[og]*gelu_f(d[3]+b1v[og]);
        }
        #pragma unroll
        for(int s=1;s<16;s<<=1){
            acc0 += __shfl_xor(acc0, s, 64);
            acc1 += __shfl_xor(acc1, s, 64);
            acc2 += __shfl_xor(acc2, s, 64);
            acc3 += __shfl_xor(acc3, s, 64);
        }
        if(m==0){
            int pix = pix0 + quad*4;                // 4 consecutive pixels
            *(float4*)(out + (size_t)b*16384 + pix) =
                make_float4(acc0+p2bv, acc1+p2bv, acc2+p2bv, acc3+p2bv);
        }
    }
}

// ============================ launch ============================
extern "C" void kernel_launch(void* const* d_in, const int* in_sizes, int n_in,
                              void* d_out, int out_size, void* d_ws, size_t ws_size,
                              hipStream_t stream){
    const float* x      = (const float*)d_in[0];
    const float* enc_w  = (const float*)d_in[1];
    const float* enc_b  = (const float*)d_in[2];
    const float* qkv_w  = (const float*)d_in[3];
    const float* qkv_b  = (const float*)d_in[4];
    const float* ao_w   = (const float*)d_in[5];
    const float* ao_b   = (const float*)d_in[6];
    const float* ln1_s  = (const float*)d_in[7];
    const float* ln1_b  = (const float*)d_in[8];
    const float* ff1_w  = (const float*)d_in[9];
    const float* ff1_b  = (const float*)d_in[10];
    const float* ff2_w  = (const float*)d_in[11];
    const float* ff2_b  = (const float*)d_in[12];
    const float* ln2_s  = (const float*)d_in[13];
    const float* ln2_b  = (const float*)d_in[14];
    const float* fc_w   = (const float*)d_in[15];
    const float* fc_b   = (const float*)d_in[16];
    const float* lift_w = (const float*)d_in[17];
    const float* lift_b = (const float*)d_in[18];
    const float* spec_wr= (const float*)d_in[19];
    const float* spec_wi= (const float*)d_in[20];
    const float* skip_w = (const float*)d_in[21];
    const float* skip_b = (const float*)d_in[22];
    const float* p1_w   = (const float*)d_in[23];
    const float* p1_b   = (const float*)d_in[24];
    const float* p2_w   = (const float*)d_in[25];
    const float* p2_b   = (const float*)d_in[26];

    // workspace: header 64 floats; FNO chunk of nb batches = nb*851968 floats
    // (v 524288 + spare 131072 [Gx uses first 1024/batch] + G 32768 +
    // Go 32768 + T 131072). Router scratch aliases the FNO region.
    int*   idx   = (int*)d_ws + 8;
    float* base  = (float*)d_ws + 64;

    size_t avail_fl = (ws_size/4 > 64) ? (ws_size/4 - 64) : 0;
    int nb = 1;
    for(int c = 32; c >= 1; c >>= 1){
        if((size_t)c*851968 <= avail_fl){ nb = c; break; }
    }

    float* hbuf  = base;                         // 262144
    float* qkvb  = hbuf + 262144;                // 786432
    float* obuf  = qkvb + 786432;                // 262144
    float* rbuf  = obuf + 262144;                // 262144

    // ---- router ----
    r_embed<<<1024,256,0,stream>>>(x, enc_w, enc_b, hbuf);
    for(int l=0;l<2;++l){
        r_qkv<<<3072,256,0,stream>>>(hbuf, qkv_w, qkv_b, l*64*192, l*192, qkvb);
        r_attn<<<128,128,0,stream>>>(qkvb, obuf);
        r_proj_res<<<1024,256,0,stream>>>(hbuf, obuf, ao_w, ao_b, l*64*64, l*64, rbuf);
        r_ln<<<64,64,0,stream>>>(rbuf, ln1_s, ln1_b, l*64, hbuf);
        r_ffn<<<4096,256,0,stream>>>(hbuf, ff1_w, ff1_b, ff2_w, ff2_b,
                                     l*64*256, l*256, l*256*64, l*64, rbuf);
        r_ln<<<64,64,0,stream>>>(rbuf, ln2_s, ln2_b, l*64, hbuf);
    }
    r_head<<<32,64,0,stream>>>(hbuf, fc_w, fc_b, idx);

    // ---- FNO, batch-chunked ----
    for(int b0 = 0; b0 < 32; b0 += nb){
        float* vC = base;                        // nb*524288
        float* Gx = vC + (size_t)nb*524288;      // nb*1024 (in spare region)
        float* G  = vC + (size_t)nb*655360;      // nb*32768
        float* Go = G  + (size_t)nb*32768;       // nb*32768
        float* T  = Go + (size_t)nb*32768;       // nb*131072

        f_lift<<<nb*2048,256,0,stream>>>(x, lift_w, lift_b, idx, b0, vC);
        for(int l=0;l<4;++l){
            if(l==0){
                f_fwd_x<<<nb,   256,0,stream>>>(x, b0, Gx);
                f_scale<<<nb*64,256,0,stream>>>(Gx, lift_w, lift_b, idx, b0, G);
            }else{
                f_fwd  <<<nb*16,256,0,stream>>>(vC, G);
            }
            f_specmul<<<nb*64, 256,0,stream>>>(G, spec_wr, spec_wi, idx, l, b0, Go);
            f_idft_h <<<nb*32, 128,0,stream>>>(Go, T);
            f_inv_w_skip<<<nb*128,128,0,stream>>>(T, vC, skip_w, skip_b, idx,
                                                  l, (l<3)?1:0, b0);
        }
        f_proj<<<nb*32,256,0,stream>>>(vC, p1_w, p1_b, p2_w, p2_b, idx, b0,
                                       (float*)d_out);
    }
}